// Round 7
// baseline (390.433 us; speedup 1.0000x reference)
//
#include <hip/hip_runtime.h>
#include <math.h>

// sequence_to_pair_block: B=4, S=2048, D=1024, P=512, H=16, C=64, out [4,512,512,64] fp32
//
// ROUND 7 = RERUN of ROUND 6 (container failed twice; R6 audited clean: no OOB,
// no hang path, wave-uniform conditional staging — same verdict as R3's flake,
// which R4's pass vindicated).
// k_gemm rebalanced to EXACTLY 256 blocks (grid 16x16). The old 17th
// nt column (yq/yk) made 272 blocks on 256 CUs -> a 16-block straggler round
// with the GPU ~94% idle for a full block-time. yq/yk now folded into every
// nt block as a third MFMA pair: A2 = g tile (gelu path), B2 = 8 rows of
// Wyq/Wyk (4 cols each per nt; MFMA n-cols 8-31 compute garbage into
// never-stored outputs). dbuf reverted (R5: +8us). k_main/k_uv/k_prep = R1.
//
// Algebra: relative_shift in the reference is an identity slice [:, :, :P], and
// central_mask_features rows 0..510 are the constant vector [1*32, -1*32] (row 511:
// [1*32, 0*32]). So the rel terms collapse to rank-1 row/col corrections U[b,i,:]
// and V[b,j,:] plus edge fixes at i==511 / j==511 (folded into k_main's store).

typedef unsigned short u16;
typedef unsigned int   u32;
typedef __attribute__((ext_vector_type(8)))  short short8;   // 8 bf16 (4 VGPRs)
typedef __attribute__((ext_vector_type(16))) float float16;  // MFMA 32x32 acc

#define SEQ 2048
#define DIMN 1024

__device__ __forceinline__ u16 f2bf(float f) {
    union { float f; u32 u; } v; v.f = f;
    u32 r = v.u + 0x7fffu + ((v.u >> 16) & 1u);   // RNE
    return (u16)(r >> 16);
}
__device__ __forceinline__ float bf2f(u16 h) {
    union { u32 u; float f; } v; v.u = ((u32)h) << 16;
    return v.f;
}
__device__ __forceinline__ void ld_g2l16(u16* lds, const u16* g) {
    __builtin_amdgcn_global_load_lds((const __attribute__((address_space(1))) u32*)g,
                                     (__attribute__((address_space(3))) u32*)lds, 16, 0, 0);
}

struct alignas(8) us4 { u16 x, y, z, w; };

// ---------------- K1: weight cvt + avgpool+gelu + pos_enc prep --------------
__global__ __launch_bounds__(256) void k_prep(
    const float* __restrict__ x,
    const float* __restrict__ Wq, const float* __restrict__ Wk,
    const float* __restrict__ Wyq, const float* __restrict__ Wyk,
    const float* __restrict__ Wpos, const float* __restrict__ bpos,
    u16* __restrict__ xds, u16* __restrict__ g,
    u16* __restrict__ wqb, u16* __restrict__ wkb,
    u16* __restrict__ wyqb, u16* __restrict__ wykb,
    float* __restrict__ peA, float* __restrict__ peD)
{
    int bk = blockIdx.x, tid = threadIdx.x;
    if (bk < 1024) {                       // fp32 -> bf16 weight conversion
        int i = (bk * 256 + tid) * 4;
        float4 a = *(const float4*)(Wq + i);
        us4 o; o.x=f2bf(a.x); o.y=f2bf(a.y); o.z=f2bf(a.z); o.w=f2bf(a.w);
        *(us4*)(wqb + i) = o;
        a = *(const float4*)(Wk + i);
        o.x=f2bf(a.x); o.y=f2bf(a.y); o.z=f2bf(a.z); o.w=f2bf(a.w);
        *(us4*)(wkb + i) = o;
        if (i < 65536) {
            a = *(const float4*)(Wyq + i);
            o.x=f2bf(a.x); o.y=f2bf(a.y); o.z=f2bf(a.z); o.w=f2bf(a.w);
            *(us4*)(wyqb + i) = o;
            a = *(const float4*)(Wyk + i);
            o.x=f2bf(a.x); o.y=f2bf(a.y); o.z=f2bf(a.z); o.w=f2bf(a.w);
            *(us4*)(wykb + i) = o;
        }
    } else if (bk < 3072) {                // avgpool(4) + exact gelu
        int r = bk - 1024;                 // row 0..2047 = b*512+p
        int d4 = tid * 4;
        int b = r >> 9, p = r & 511;
        const float* base = x + ((size_t)(b * SEQ + p * 4)) * DIMN + d4;
        float4 a0 = *(const float4*)(base);
        float4 a1 = *(const float4*)(base + DIMN);
        float4 a2 = *(const float4*)(base + 2 * DIMN);
        float4 a3 = *(const float4*)(base + 3 * DIMN);
        float m0=(a0.x+a1.x+a2.x+a3.x)*0.25f, m1=(a0.y+a1.y+a2.y+a3.y)*0.25f;
        float m2=(a0.z+a1.z+a2.z+a3.z)*0.25f, m3=(a0.w+a1.w+a2.w+a3.w)*0.25f;
        size_t o = (size_t)r * DIMN + d4;
        us4 xo; xo.x=f2bf(m0); xo.y=f2bf(m1); xo.z=f2bf(m2); xo.w=f2bf(m3);
        *(us4*)(xds + o) = xo;
        const float is2 = 0.70710678118654752f;
        us4 go;
        go.x = f2bf(0.5f*m0*(1.f+erff(m0*is2)));
        go.y = f2bf(0.5f*m1*(1.f+erff(m1*is2)));
        go.z = f2bf(0.5f*m2*(1.f+erff(m2*is2)));
        go.w = f2bf(0.5f*m3*(1.f+erff(m3*is2)));
        *(us4*)(g + o) = go;
    } else {                               // pos_enc constants: peA (j<511), peD = pe(511)-peA
        int t = (bk - 3072) * 256 + tid;
        if (t < 1024) {
            const float* wr = Wpos + t * 64;
            float s1 = 0.f, s2 = 0.f;
            for (int m = 0; m < 32; m++)  s1 += wr[m];
            for (int m = 32; m < 64; m++) s2 += wr[m];
            peA[t] = s1 - s2 + bpos[t];    // feat = [1..1, -1..-1]
            peD[t] = s2;                   // row 511 adds back the signed half
        }
    }
}

// ---------------- K2: fused GEMM, 256 balanced blocks -----------------------
// Block (nt, mt): q cols [nt*64,+64) and k cols [nt*64,+64) from A=xds tile
// (128 rows), PLUS yq/yk cols [nt*4,+4) from A2=g tile against B2 = 8 staged
// rows of Wyq/Wyk (MFMA n-cols 8..31 are garbage, never stored).
// BK=32, 10 MFMAs per barrier pair.
// Swizzled layout for q/k: chunk(b,h,ks,kh,row) = ((b*16+h)*8 + ks*2+kh)*512 + row,
// 8 bf16 per chunk = q[b,row,h, ks*16+kh*8 .. +8]  -> MFMA frag = 16B/lane coalesced.
__global__ __launch_bounds__(256) void k_gemm(
    const u16* __restrict__ xds, const u16* __restrict__ g,
    const u16* __restrict__ wqb, const u16* __restrict__ wkb,
    const u16* __restrict__ wyqb, const u16* __restrict__ wykb,
    u16* __restrict__ qA, u16* __restrict__ kB,
    float* __restrict__ yqlin, float* __restrict__ yklin)
{
    __shared__ alignas(16) u16 Al[128 * 32];    // xds tile
    __shared__ alignas(16) u16 A2l[128 * 32];   // g tile (for yq/yk)
    __shared__ alignas(16) u16 B0l[64 * 32];    // Wq cols
    __shared__ alignas(16) u16 B1l[64 * 32];    // Wk cols
    __shared__ alignas(16) u16 B2l[32 * 32];    // rows 0-3: Wyq[nt*4+r], 4-7: Wyk; 8-31 stale/unused
    int nt = blockIdx.x, mt = blockIdx.y;
    int col0 = nt * 64;
    int r0 = mt * 128;
    int tid = threadIdx.x;
    int wv = tid >> 6, ln = tid & 63;
    int lane31 = ln & 31, half = ln >> 5;
    float16 aq0, aq1, ak0, ak1, ay;
#pragma unroll
    for (int e = 0; e < 16; e++) { aq0[e]=0.f; aq1[e]=0.f; ak0[e]=0.f; ak1[e]=0.f; ay[e]=0.f; }
    int row_l = wv * 32 + lane31;
    int swzA = (row_l >> 1) & 3;
    int colL0 = lane31, colL1 = 32 + lane31;
    int swzB0 = (colL0 >> 1) & 3, swzB1 = (colL1 >> 1) & 3;
    // B2 staging source (used by wave 0 only; lanes 32-63 write harmless dups)
    int yrow = (ln >> 2) & 7, yccs = ln & 3;
    int ycc = yccs ^ ((yrow >> 1) & 3);
    const u16* ysrc = (yrow < 4 ? wyqb + (size_t)(nt * 4 + yrow) * 1024
                                : wykb + (size_t)(nt * 4 + yrow - 4) * 1024) + ycc * 8;

    for (int k0 = 0; k0 < 1024; k0 += 32) {
        // stage A + A2 (512 x 16B chunks each) and B0/B1 (256 chunks each)
#pragma unroll
        for (int q = 0; q < 2; q++) {
            int n = q * 256 + wv * 64 + ln;
            int row = n >> 2, ccs = n & 3;
            int cc = ccs ^ ((row >> 1) & 3);
            ld_g2l16(Al + (size_t)(q * 256 + wv * 64) * 8,
                     xds + (size_t)(r0 + row) * 1024 + k0 + cc * 8);
            ld_g2l16(A2l + (size_t)(q * 256 + wv * 64) * 8,
                     g + (size_t)(r0 + row) * 1024 + k0 + cc * 8);
        }
        {
            int n = wv * 64 + ln;
            int row = n >> 2, ccs = n & 3;
            int cc = ccs ^ ((row >> 1) & 3);
            ld_g2l16(B0l + (size_t)(wv * 64) * 8,
                     wqb + (size_t)(col0 + row) * 1024 + k0 + cc * 8);
            ld_g2l16(B1l + (size_t)(wv * 64) * 8,
                     wkb + (size_t)(col0 + row) * 1024 + k0 + cc * 8);
        }
        if (wv == 0) ld_g2l16(B2l, ysrc + k0);   // full wave: 8 real rows + dups
        __syncthreads();   // drains vmcnt(0): staging visible
        short8 a0  = *(const short8*)(Al  + (row_l * 4 + ((0 + half) ^ swzA)) * 8);
        short8 a1  = *(const short8*)(Al  + (row_l * 4 + ((2 + half) ^ swzA)) * 8);
        short8 ag0 = *(const short8*)(A2l + (row_l * 4 + ((0 + half) ^ swzA)) * 8);
        short8 ag1 = *(const short8*)(A2l + (row_l * 4 + ((2 + half) ^ swzA)) * 8);
        short8 q00 = *(const short8*)(B0l + (colL0 * 4 + ((0 + half) ^ swzB0)) * 8);
        short8 q01 = *(const short8*)(B0l + (colL0 * 4 + ((2 + half) ^ swzB0)) * 8);
        short8 q10 = *(const short8*)(B0l + (colL1 * 4 + ((0 + half) ^ swzB1)) * 8);
        short8 q11 = *(const short8*)(B0l + (colL1 * 4 + ((2 + half) ^ swzB1)) * 8);
        short8 k00 = *(const short8*)(B1l + (colL0 * 4 + ((0 + half) ^ swzB0)) * 8);
        short8 k01 = *(const short8*)(B1l + (colL0 * 4 + ((2 + half) ^ swzB0)) * 8);
        short8 k10 = *(const short8*)(B1l + (colL1 * 4 + ((0 + half) ^ swzB1)) * 8);
        short8 k11 = *(const short8*)(B1l + (colL1 * 4 + ((2 + half) ^ swzB1)) * 8);
        short8 y0  = *(const short8*)(B2l + (lane31 * 4 + ((0 + half) ^ swzB0)) * 8);
        short8 y1  = *(const short8*)(B2l + (lane31 * 4 + ((2 + half) ^ swzB0)) * 8);
        aq0 = __builtin_amdgcn_mfma_f32_32x32x16_bf16(a0, q00, aq0, 0, 0, 0);
        aq0 = __builtin_amdgcn_mfma_f32_32x32x16_bf16(a1, q01, aq0, 0, 0, 0);
        aq1 = __builtin_amdgcn_mfma_f32_32x32x16_bf16(a0, q10, aq1, 0, 0, 0);
        aq1 = __builtin_amdgcn_mfma_f32_32x32x16_bf16(a1, q11, aq1, 0, 0, 0);
        ak0 = __builtin_amdgcn_mfma_f32_32x32x16_bf16(a0, k00, ak0, 0, 0, 0);
        ak0 = __builtin_amdgcn_mfma_f32_32x32x16_bf16(a1, k01, ak0, 0, 0, 0);
        ak1 = __builtin_amdgcn_mfma_f32_32x32x16_bf16(a0, k10, ak1, 0, 0, 0);
        ak1 = __builtin_amdgcn_mfma_f32_32x32x16_bf16(a1, k11, ak1, 0, 0, 0);
        ay  = __builtin_amdgcn_mfma_f32_32x32x16_bf16(ag0, y0, ay, 0, 0, 0);
        ay  = __builtin_amdgcn_mfma_f32_32x32x16_bf16(ag1, y1, ay, 0, 0, 0);
        __syncthreads();
    }
    // epilogue: C layout col=lane&31, row=(reg&3)+8*(reg>>2)+4*(lane>>5)
#pragma unroll
    for (int sel = 0; sel < 4; sel++) {
        int ct = sel & 1;                 // column sub-tile
        bool isq = (sel < 2);             // q vs k
#pragma unroll
        for (int reg = 0; reg < 16; reg++) {
            float v = (sel == 0) ? aq0[reg] : (sel == 1) ? aq1[reg]
                    : (sel == 2) ? ak0[reg] : ak1[reg];
            int rowp = (reg & 3) + 8 * (reg >> 2) + 4 * half;
            int r = r0 + wv * 32 + rowp;
            int col = col0 + ct * 32 + lane31;
            int bb = r >> 9, ii = r & 511;
            int h = col >> 6, c = col & 63;
            size_t chunk = ((size_t)((bb * 16 + h) * 8 + (c >> 3))) * 512 + ii;
            u16* dst = isq ? qA : kB;
            dst[chunk * 8 + (c & 7)] = f2bf(v);
        }
    }
    // y epilogue: ay cols 0-3 -> yq[nt*4+col], cols 4-7 -> yk[nt*4+col-4]
    if (lane31 < 8) {
        float* dst = (lane31 < 4) ? yqlin : yklin;
        int dcol = nt * 4 + (lane31 & 3);
#pragma unroll
        for (int reg = 0; reg < 16; reg++) {
            int rowp = (reg & 3) + 8 * (reg >> 2) + 4 * half;
            int r = r0 + wv * 32 + rowp;
            dst[(size_t)r * 64 + dcol] = ay[reg];
        }
    }
}

// ---------------- K3: per-row U/V/dU/dV vectors ------------------------------
__global__ __launch_bounds__(64) void k_uv(
    const u16* __restrict__ qA, const u16* __restrict__ kB,
    const float* __restrict__ yqlin, const float* __restrict__ yklin,
    const float* __restrict__ peA, const float* __restrict__ peD,
    const float* __restrict__ qbias, const float* __restrict__ kbias,
    const float* __restrict__ Wout, const float* __restrict__ bout,
    float* __restrict__ U, float* __restrict__ V,
    float* __restrict__ dU, float* __restrict__ dV)
{
    __shared__ float qrow[1024], krow[1024];
    __shared__ float RA[4][16];
    int r = blockIdx.x; int b = r >> 9, i = r & 511;
    int t = threadIdx.x;
#pragma unroll
    for (int u = 0; u < 2; u++) {
        int cidx = t * 2 + u;
        int h = cidx >> 3, sub = cidx & 7;
        size_t chunk = ((size_t)((b * 16 + h) * 8 + sub)) * 512 + i;
        const u16* sq = qA + chunk * 8;
        const u16* sk = kB + chunk * 8;
        int c0 = h * 64 + sub * 8;
#pragma unroll
        for (int e = 0; e < 8; e++) { qrow[c0 + e] = bf2f(sq[e]); krow[c0 + e] = bf2f(sk[e]); }
    }
    __syncthreads();
    {
        int h = t & 15, which = t >> 4;   // 0:RAq 1:RDq 2:RAk 3:RDk
        const float* rw = (which < 2) ? qrow : krow;
        const float* bs = (which < 2) ? qbias : kbias;
        const float* pe = (which & 1) ? peD : peA;
        float s = 0.f;
        for (int c = 0; c < 64; c++) s += (rw[h * 64 + c] + bs[h * 64 + c]) * pe[h * 64 + c];
        RA[which][h] = s;
    }
    __syncthreads();
    int d = t;
    float uA = 0.f, uD = 0.f, vA = 0.f, vD = 0.f;
#pragma unroll
    for (int hh = 0; hh < 16; hh++) {
        float w = Wout[d * 16 + hh];
        uA += RA[0][hh] * w; uD += RA[1][hh] * w;
        vA += RA[2][hh] * w; vD += RA[3][hh] * w;
    }
    size_t o = (size_t)r * 64 + d;
    U[o]  = yqlin[o] + 0.5f * uA + bout[d];
    dU[o] = 0.5f * uD;
    V[o]  = yklin[o] + 0.5f * vA;
    dV[o] = 0.5f * vD;
}

// ---------------- K4: main pair kernel (edge corrections folded in) ---------
// 32x32 (i,j) tile per block.  Stage 1: 4 waves x 4 heads of Q.K^T MFMAs.
// Stage 2: A[pos][h] through LDS (bf16, stride 20) -> MFMA (pos x h)@Wout so the
// d dim is lane-contiguous for 128B store segments.  + U(i) + V(j); at the
// global edges (i==511 / j==511) also + dV(j) / dU(i).  Nontemporal stores:
// out is write-once, never re-read -> keep qA/kB/U/V resident in L2
// (R4 measured plain stores ~18us SLOWER than NT).
__global__ __launch_bounds__(256) void k_main(
    const u16* __restrict__ qA, const u16* __restrict__ kB,
    const float* __restrict__ Wout,
    const float* __restrict__ U, const float* __restrict__ V,
    const float* __restrict__ dU, const float* __restrict__ dV,
    float* __restrict__ out)
{
    __shared__ alignas(16) u16 Asm[1024 * 20];   // [pos 1024][16 h + 4 pad] bf16, 40 KB
    int jt = blockIdx.x, it = blockIdx.y, b = blockIdx.z;
    int i0 = it * 32, j0 = jt * 32;
    int tid = threadIdx.x, wv = tid >> 6, ln = tid & 63;
    int lane31 = ln & 31, half = ln >> 5;

    float16 acc[4];
#pragma unroll
    for (int hh = 0; hh < 4; hh++) {
        int h = wv * 4 + hh;
        size_t hbase = ((size_t)(b * 16 + h)) * 8;
        short8 qa[4], kb4[4];
#pragma unroll
        for (int ks = 0; ks < 4; ks++) {
            size_t ch = (hbase + ks * 2 + half) * 512;
            qa[ks]  = *(const short8*)(qA + (ch + i0 + lane31) * 8);   // A: m=i, k contiguous 8
            kb4[ks] = *(const short8*)(kB + (ch + j0 + lane31) * 8);   // B: n=j, k contiguous 8
        }
        float16 a;
#pragma unroll
        for (int e = 0; e < 16; e++) a[e] = 0.f;
#pragma unroll
        for (int ks = 0; ks < 4; ks++)
            a = __builtin_amdgcn_mfma_f32_32x32x16_bf16(qa[ks], kb4[ks], a, 0, 0, 0);
        acc[hh] = a;
    }
    // scatter A to LDS as bf16, 2 heads packed per dword
#pragma unroll
    for (int reg = 0; reg < 16; reg++) {
        int row = (reg & 3) + 8 * (reg >> 2) + 4 * half;   // i_local
        int pos = row * 32 + lane31;                       // pos = i_local*32 + j_local
        u32 pk0 = (u32)f2bf(acc[0][reg]) | ((u32)f2bf(acc[1][reg]) << 16);
        u32 pk1 = (u32)f2bf(acc[2][reg]) | ((u32)f2bf(acc[3][reg]) << 16);
        u32* bp = (u32*)(Asm + pos * 20 + wv * 4);
        bp[0] = pk0; bp[1] = pk1;
    }
    // Wout B-frags: B[k=h][n=d], lane: d=dt*32+lane31, h=half*8+jj
    short8 wfr[2];
#pragma unroll
    for (int dt = 0; dt < 2; dt++) {
        const float* wp = Wout + (dt * 32 + lane31) * 16 + half * 8;
        float4 w0 = *(const float4*)(wp);
        float4 w1 = *(const float4*)(wp + 4);
        short8 t8;
        t8[0]=(short)f2bf(w0.x); t8[1]=(short)f2bf(w0.y); t8[2]=(short)f2bf(w0.z); t8[3]=(short)f2bf(w0.w);
        t8[4]=(short)f2bf(w1.x); t8[5]=(short)f2bf(w1.y); t8[6]=(short)f2bf(w1.z); t8[7]=(short)f2bf(w1.w);
        wfr[dt] = t8;
    }
    // V is j-indexed: same for every i_local -> preload once
    float vreg[2][16];
#pragma unroll
    for (int dt = 0; dt < 2; dt++)
#pragma unroll
        for (int reg = 0; reg < 16; reg++) {
            int row = (reg & 3) + 8 * (reg >> 2) + 4 * half;
            vreg[dt][reg] = V[((size_t)(b * 512 + j0 + row)) * 64 + dt * 32 + lane31];
        }
    __syncthreads();
    bool ej_blk = (jt == 15);             // this block holds column j==511 (row31, half==1, reg 15)
    // projection: per i_local row (M = 32 j's), N = d
    for (int m = 0; m < 8; m++) {
        int il = wv * 8 + m;
        const u16* ap = Asm + (il * 32 + lane31) * 20 + half * 8;
        union { short8 v; uint2 q[2]; } au;
        au.q[0] = *(const uint2*)(ap);
        au.q[1] = *(const uint2*)(ap + 4);
        int ig = i0 + il;
        bool ei = (it == 15) && (il == 31);   // this wave's row is i==511
        size_t rowbase = (size_t)(b * 512 + ig);
        size_t jbase = (size_t)(b * 512 + j0);
#pragma unroll
        for (int dt = 0; dt < 2; dt++) {
            int dcol = dt * 32 + lane31;
            float16 z;
#pragma unroll
            for (int e = 0; e < 16; e++) z[e] = 0.f;
            float16 pa = __builtin_amdgcn_mfma_f32_32x32x16_bf16(au.v, wfr[dt], z, 0, 0, 0);
            float uval = U[rowbase * 64 + dcol];
            float duv = 0.f;
            if (ej_blk && half) duv = dU[rowbase * 64 + dcol];   // j==511 column fix
            float* ob = out + (rowbase * 512 + j0) * 64 + dcol;
#pragma unroll
            for (int reg = 0; reg < 16; reg++) {
                int row = (reg & 3) + 8 * (reg >> 2) + 4 * half;   // j_local
                float v = pa[reg] + uval + vreg[dt][reg];
                if (ei) v += dV[(jbase + row) * 64 + dcol];        // i==511 row fix
                if (reg == 15) v += duv;                           // duv==0 unless edge
                __builtin_nontemporal_store(v, ob + (size_t)row * 64);
            }
        }
    }
}

extern "C" void kernel_launch(void* const* d_in, const int* in_sizes, int n_in,
                              void* d_out, int out_size, void* d_ws, size_t ws_size,
                              hipStream_t stream)
{
    const float* x    = (const float*)d_in[0];
    const float* Wq   = (const float*)d_in[1];
    const float* Wk   = (const float*)d_in[2];
    const float* Wpos = (const float*)d_in[3];
    const float* bpos = (const float*)d_in[4];
    const float* qb   = (const float*)d_in[5];
    const float* kb   = (const float*)d_in[6];
    const float* Wout = (const float*)d_in[7];
    const float* bout = (const float*)d_in[8];
    const float* Wyq  = (const float*)d_in[9];
    const float* Wyk  = (const float*)d_in[10];
    float* out = (float*)d_out;
    char* w = (char*)d_ws;
    // workspace layout (~24.4 MB)
    u16* xds   = (u16*)(w + 0);          // 4 MB  [2048][1024] bf16
    u16* g     = (u16*)(w + 4194304);    // 4 MB
    u16* wqb   = (u16*)(w + 8388608);    // 2 MB
    u16* wkb   = (u16*)(w + 10485760);   // 2 MB
    u16* wyqb  = (u16*)(w + 12582912);   // 128 KB
    u16* wykb  = (u16*)(w + 12713984);   // 128 KB
    u16* qA    = (u16*)(w + 12845056);   // 4 MB swizzled
    u16* kB2   = (u16*)(w + 17039360);   // 4 MB swizzled
    float* yqlin = (float*)(w + 21233664); // 512 KB
    float* yklin = (float*)(w + 21757952); // 512 KB
    float* peA   = (float*)(w + 22282240); // 4 KB
    float* peD   = (float*)(w + 22286336); // 4 KB
    float* U     = (float*)(w + 22290432); // 512 KB
    float* V     = (float*)(w + 22814720); // 512 KB
    float* dU    = (float*)(w + 23339008); // 512 KB
    float* dV    = (float*)(w + 23863296); // 512 KB

    k_prep<<<dim3(3076), dim3(256), 0, stream>>>(x, Wq, Wk, Wyq, Wyk, Wpos, bpos,
                                                 xds, g, wqb, wkb, wyqb, wykb, peA, peD);
    k_gemm<<<dim3(16, 16), dim3(256), 0, stream>>>(xds, g, wqb, wkb, wyqb, wykb,
                                                   qA, kB2, yqlin, yklin);
    k_uv<<<dim3(2048), dim3(64), 0, stream>>>(qA, kB2, yqlin, yklin, peA, peD,
                                              qb, kb, Wout, bout, U, V, dU, dV);
    k_main<<<dim3(16, 16, 4), dim3(256), 0, stream>>>(qA, kB2, Wout, U, V, dU, dV, out);
}

// Round 8
// 367.924 us; speedup vs baseline: 1.0612x; 1.0612x over previous
//
#include <hip/hip_runtime.h>
#include <math.h>

// sequence_to_pair_block: B=4, S=2048, D=1024, P=512, H=16, C=64, out [4,512,512,64] fp32
//
// ROUND 8 = REVERT TO R0 BASELINE (best measured: 370.2us prior session,
// 370.4us this session — the most-replicated point). Session ledger: R0=370.4,
// R1(fuse+fold+NT)=375.3, R4(plain+Upre)=393.8, R5(dbuf)=383.3, R7(256blk)=390.4.
// Five theory-sound variants span 370-394 ≈ harness noise band (fills swing
// ±5% across rounds; ~170us/iter of 1.07GB poison-fill sits inside the timed
// window). Controllable kernel time ~100-130us is at its memory floor
// (k_main ~50-60us at 6.4TB/s write BW). Reverting to best-known and closing.
//
// Algebra: relative_shift in the reference is an identity slice [:, :, :P], and
// central_mask_features rows 0..510 are the constant vector [1*32, -1*32] (row 511:
// [1*32, 0*32]). So the rel terms collapse to rank-1 row/col corrections U[b,i,:]
// and V[b,j,:] plus edge fixes at i==511 / j==511.

typedef unsigned short u16;
typedef unsigned int   u32;
typedef __attribute__((ext_vector_type(8)))  short short8;   // 8 bf16 (4 VGPRs)
typedef __attribute__((ext_vector_type(16))) float float16;  // MFMA 32x32 acc

#define SEQ 2048
#define DIMN 1024

__device__ __forceinline__ u16 f2bf(float f) {
    union { float f; u32 u; } v; v.f = f;
    u32 r = v.u + 0x7fffu + ((v.u >> 16) & 1u);   // RNE
    return (u16)(r >> 16);
}
__device__ __forceinline__ float bf2f(u16 h) {
    union { u32 u; float f; } v; v.u = ((u32)h) << 16;
    return v.f;
}
__device__ __forceinline__ void ld_g2l16(u16* lds, const u16* g) {
    __builtin_amdgcn_global_load_lds((const __attribute__((address_space(1))) u32*)g,
                                     (__attribute__((address_space(3))) u32*)lds, 16, 0, 0);
}

struct alignas(8) us4 { u16 x, y, z, w; };

// ---------------- K1: weight cvt + avgpool+gelu + pos_enc prep --------------
__global__ __launch_bounds__(256) void k_prep(
    const float* __restrict__ x,
    const float* __restrict__ Wq, const float* __restrict__ Wk,
    const float* __restrict__ Wyq, const float* __restrict__ Wyk,
    const float* __restrict__ Wpos, const float* __restrict__ bpos,
    u16* __restrict__ xds, u16* __restrict__ g,
    u16* __restrict__ wqb, u16* __restrict__ wkb,
    u16* __restrict__ wyqb, u16* __restrict__ wykb,
    float* __restrict__ peA, float* __restrict__ peD)
{
    int bk = blockIdx.x, tid = threadIdx.x;
    if (bk < 1024) {                       // fp32 -> bf16 weight conversion
        int i = (bk * 256 + tid) * 4;
        float4 a = *(const float4*)(Wq + i);
        us4 o; o.x=f2bf(a.x); o.y=f2bf(a.y); o.z=f2bf(a.z); o.w=f2bf(a.w);
        *(us4*)(wqb + i) = o;
        a = *(const float4*)(Wk + i);
        o.x=f2bf(a.x); o.y=f2bf(a.y); o.z=f2bf(a.z); o.w=f2bf(a.w);
        *(us4*)(wkb + i) = o;
        if (i < 65536) {
            a = *(const float4*)(Wyq + i);
            o.x=f2bf(a.x); o.y=f2bf(a.y); o.z=f2bf(a.z); o.w=f2bf(a.w);
            *(us4*)(wyqb + i) = o;
            a = *(const float4*)(Wyk + i);
            o.x=f2bf(a.x); o.y=f2bf(a.y); o.z=f2bf(a.z); o.w=f2bf(a.w);
            *(us4*)(wykb + i) = o;
        }
    } else if (bk < 3072) {                // avgpool(4) + exact gelu
        int r = bk - 1024;                 // row 0..2047 = b*512+p
        int d4 = tid * 4;
        int b = r >> 9, p = r & 511;
        const float* base = x + ((size_t)(b * SEQ + p * 4)) * DIMN + d4;
        float4 a0 = *(const float4*)(base);
        float4 a1 = *(const float4*)(base + DIMN);
        float4 a2 = *(const float4*)(base + 2 * DIMN);
        float4 a3 = *(const float4*)(base + 3 * DIMN);
        float m0=(a0.x+a1.x+a2.x+a3.x)*0.25f, m1=(a0.y+a1.y+a2.y+a3.y)*0.25f;
        float m2=(a0.z+a1.z+a2.z+a3.z)*0.25f, m3=(a0.w+a1.w+a2.w+a3.w)*0.25f;
        size_t o = (size_t)r * DIMN + d4;
        us4 xo; xo.x=f2bf(m0); xo.y=f2bf(m1); xo.z=f2bf(m2); xo.w=f2bf(m3);
        *(us4*)(xds + o) = xo;
        const float is2 = 0.70710678118654752f;
        us4 go;
        go.x = f2bf(0.5f*m0*(1.f+erff(m0*is2)));
        go.y = f2bf(0.5f*m1*(1.f+erff(m1*is2)));
        go.z = f2bf(0.5f*m2*(1.f+erff(m2*is2)));
        go.w = f2bf(0.5f*m3*(1.f+erff(m3*is2)));
        *(us4*)(g + o) = go;
    } else {                               // pos_enc constants: peA (j<511), peD = pe(511)-peA
        int t = (bk - 3072) * 256 + tid;
        if (t < 1024) {
            const float* wr = Wpos + t * 64;
            float s1 = 0.f, s2 = 0.f;
            for (int m = 0; m < 32; m++)  s1 += wr[m];
            for (int m = 32; m < 64; m++) s2 += wr[m];
            peA[t] = s1 - s2 + bpos[t];    // feat = [1..1, -1..-1]
            peD[t] = s2;                   // row 511 adds back the signed half
        }
    }
}

// ---------------- K2: fused GEMM  q,k (swizzled bf16) + yq,yk (fp32) --------
// nt<16: q cols, nt<32: k cols, nt==32: yq, nt==33: yk.  Tile 128x64, BK=32.
// Swizzled layout for q/k: chunk(b,h,ks,kh,row) = ((b*16+h)*8 + ks*2+kh)*512 + row,
// 8 bf16 per chunk = q[b,row,h, ks*16+kh*8 .. +8]  -> MFMA frag = 16B/lane coalesced.
__global__ __launch_bounds__(256) void k_gemm(
    const u16* __restrict__ xds, const u16* __restrict__ g,
    const u16* __restrict__ wqb, const u16* __restrict__ wkb,
    const u16* __restrict__ wyqb, const u16* __restrict__ wykb,
    u16* __restrict__ qA, u16* __restrict__ kB,
    float* __restrict__ yqlin, float* __restrict__ yklin)
{
    __shared__ alignas(16) u16 Al[128 * 32];
    __shared__ alignas(16) u16 Bl[64 * 32];
    int nt = blockIdx.x, mt = blockIdx.y;
    const u16* Asrc; const u16* Wsrc; int col0; int mode;
    if (nt < 16)       { Asrc = xds; Wsrc = wqb;  col0 = nt * 64;        mode = 0; }
    else if (nt < 32)  { Asrc = xds; Wsrc = wkb;  col0 = (nt - 16) * 64; mode = 1; }
    else if (nt == 32) { Asrc = g;   Wsrc = wyqb; col0 = 0;              mode = 2; }
    else               { Asrc = g;   Wsrc = wykb; col0 = 0;              mode = 3; }
    int r0 = mt * 128;
    int tid = threadIdx.x;
    int wv = tid >> 6, ln = tid & 63;
    int lane31 = ln & 31, half = ln >> 5;
    float16 acc0, acc1;
#pragma unroll
    for (int e = 0; e < 16; e++) { acc0[e] = 0.f; acc1[e] = 0.f; }
    int row_l = wv * 32 + lane31;
    int swzA = (row_l >> 1) & 3;
    int colL0 = lane31, colL1 = 32 + lane31;
    int swzB0 = (colL0 >> 1) & 3, swzB1 = (colL1 >> 1) & 3;

    for (int k0 = 0; k0 < 1024; k0 += 32) {
        // stage A (512 x 16B chunks) and B (256 chunks) with xor-swizzle vs bank conflicts
#pragma unroll
        for (int q = 0; q < 2; q++) {
            int n = q * 256 + wv * 64 + ln;
            int row = n >> 2, ccs = n & 3;
            int cc = ccs ^ ((row >> 1) & 3);
            ld_g2l16(Al + (size_t)(q * 256 + wv * 64) * 8,
                     Asrc + (size_t)(r0 + row) * 1024 + k0 + cc * 8);
        }
        {
            int n = wv * 64 + ln;
            int row = n >> 2, ccs = n & 3;
            int cc = ccs ^ ((row >> 1) & 3);
            ld_g2l16(Bl + (size_t)(wv * 64) * 8,
                     Wsrc + (size_t)(col0 + row) * 1024 + k0 + cc * 8);
        }
        __syncthreads();   // drains vmcnt(0): staging visible
        short8 a0  = *(const short8*)(Al + (row_l * 4 + ((0 + half) ^ swzA)) * 8);
        short8 a1  = *(const short8*)(Al + (row_l * 4 + ((2 + half) ^ swzA)) * 8);
        short8 b00 = *(const short8*)(Bl + (colL0 * 4 + ((0 + half) ^ swzB0)) * 8);
        short8 b01 = *(const short8*)(Bl + (colL0 * 4 + ((2 + half) ^ swzB0)) * 8);
        short8 b10 = *(const short8*)(Bl + (colL1 * 4 + ((0 + half) ^ swzB1)) * 8);
        short8 b11 = *(const short8*)(Bl + (colL1 * 4 + ((2 + half) ^ swzB1)) * 8);
        acc0 = __builtin_amdgcn_mfma_f32_32x32x16_bf16(a0, b00, acc0, 0, 0, 0);
        acc0 = __builtin_amdgcn_mfma_f32_32x32x16_bf16(a1, b01, acc0, 0, 0, 0);
        acc1 = __builtin_amdgcn_mfma_f32_32x32x16_bf16(a0, b10, acc1, 0, 0, 0);
        acc1 = __builtin_amdgcn_mfma_f32_32x32x16_bf16(a1, b11, acc1, 0, 0, 0);
        __syncthreads();
    }
    // epilogue: C layout col=lane&31, row=(reg&3)+8*(reg>>2)+4*(lane>>5)
#pragma unroll
    for (int ct = 0; ct < 2; ct++) {
#pragma unroll
        for (int reg = 0; reg < 16; reg++) {
            float v = ct ? acc1[reg] : acc0[reg];
            int rowp = (reg & 3) + 8 * (reg >> 2) + 4 * half;
            int r = r0 + wv * 32 + rowp;
            int col = col0 + ct * 32 + lane31;
            if (mode <= 1) {
                int bb = r >> 9, ii = r & 511;
                int h = col >> 6, c = col & 63;
                size_t chunk = ((size_t)((bb * 16 + h) * 8 + (c >> 3))) * 512 + ii;
                u16* dst = (mode == 0) ? qA : kB;
                dst[chunk * 8 + (c & 7)] = f2bf(v);
            } else {
                float* dst = (mode == 2) ? yqlin : yklin;
                dst[(size_t)r * 64 + col] = v;
            }
        }
    }
}

// ---------------- K3: per-row U/V/dU/dV vectors ------------------------------
__global__ __launch_bounds__(64) void k_uv(
    const u16* __restrict__ qA, const u16* __restrict__ kB,
    const float* __restrict__ yqlin, const float* __restrict__ yklin,
    const float* __restrict__ peA, const float* __restrict__ peD,
    const float* __restrict__ qbias, const float* __restrict__ kbias,
    const float* __restrict__ Wout, const float* __restrict__ bout,
    float* __restrict__ U, float* __restrict__ V,
    float* __restrict__ dU, float* __restrict__ dV)
{
    __shared__ float qrow[1024], krow[1024];
    __shared__ float RA[4][16];
    int r = blockIdx.x; int b = r >> 9, i = r & 511;
    int t = threadIdx.x;
#pragma unroll
    for (int u = 0; u < 2; u++) {
        int cidx = t * 2 + u;
        int h = cidx >> 3, sub = cidx & 7;
        size_t chunk = ((size_t)((b * 16 + h) * 8 + sub)) * 512 + i;
        const u16* sq = qA + chunk * 8;
        const u16* sk = kB + chunk * 8;
        int c0 = h * 64 + sub * 8;
#pragma unroll
        for (int e = 0; e < 8; e++) { qrow[c0 + e] = bf2f(sq[e]); krow[c0 + e] = bf2f(sk[e]); }
    }
    __syncthreads();
    {
        int h = t & 15, which = t >> 4;   // 0:RAq 1:RDq 2:RAk 3:RDk
        const float* rw = (which < 2) ? qrow : krow;
        const float* bs = (which < 2) ? qbias : kbias;
        const float* pe = (which & 1) ? peD : peA;
        float s = 0.f;
        for (int c = 0; c < 64; c++) s += (rw[h * 64 + c] + bs[h * 64 + c]) * pe[h * 64 + c];
        RA[which][h] = s;
    }
    __syncthreads();
    int d = t;
    float uA = 0.f, uD = 0.f, vA = 0.f, vD = 0.f;
#pragma unroll
    for (int hh = 0; hh < 16; hh++) {
        float w = Wout[d * 16 + hh];
        uA += RA[0][hh] * w; uD += RA[1][hh] * w;
        vA += RA[2][hh] * w; vD += RA[3][hh] * w;
    }
    size_t o = (size_t)r * 64 + d;
    U[o]  = yqlin[o] + 0.5f * uA + bout[d];
    dU[o] = 0.5f * uD;
    V[o]  = yklin[o] + 0.5f * vA;
    dV[o] = 0.5f * vD;
}

// ---------------- K4: main pair kernel --------------------------------------
// 32x32 (i,j) tile per block.  Stage 1: 4 waves x 4 heads of Q.K^T MFMAs.
// Stage 2: A[pos][h] through LDS (bf16, stride 20) -> MFMA (pos x h)@Wout so the
// d dim is lane-contiguous for 128B store segments.  + U(i) + V(j).
__global__ __launch_bounds__(256) void k_main(
    const u16* __restrict__ qA, const u16* __restrict__ kB,
    const float* __restrict__ Wout,
    const float* __restrict__ U, const float* __restrict__ V,
    float* __restrict__ out)
{
    __shared__ alignas(16) u16 Asm[1024 * 20];   // [pos 1024][16 h + 4 pad] bf16, 40 KB
    int jt = blockIdx.x, it = blockIdx.y, b = blockIdx.z;
    int i0 = it * 32, j0 = jt * 32;
    int tid = threadIdx.x, wv = tid >> 6, ln = tid & 63;
    int lane31 = ln & 31, half = ln >> 5;

    float16 acc[4];
#pragma unroll
    for (int hh = 0; hh < 4; hh++) {
        int h = wv * 4 + hh;
        size_t hbase = ((size_t)(b * 16 + h)) * 8;
        short8 qa[4], kb4[4];
#pragma unroll
        for (int ks = 0; ks < 4; ks++) {
            size_t ch = (hbase + ks * 2 + half) * 512;
            qa[ks]  = *(const short8*)(qA + (ch + i0 + lane31) * 8);   // A: m=i, k contiguous 8
            kb4[ks] = *(const short8*)(kB + (ch + j0 + lane31) * 8);   // B: n=j, k contiguous 8
        }
        float16 a;
#pragma unroll
        for (int e = 0; e < 16; e++) a[e] = 0.f;
#pragma unroll
        for (int ks = 0; ks < 4; ks++)
            a = __builtin_amdgcn_mfma_f32_32x32x16_bf16(qa[ks], kb4[ks], a, 0, 0, 0);
        acc[hh] = a;
    }
    // scatter A to LDS as bf16, 2 heads packed per dword
#pragma unroll
    for (int reg = 0; reg < 16; reg++) {
        int row = (reg & 3) + 8 * (reg >> 2) + 4 * half;   // i_local
        int pos = row * 32 + lane31;                       // pos = i_local*32 + j_local
        u32 pk0 = (u32)f2bf(acc[0][reg]) | ((u32)f2bf(acc[1][reg]) << 16);
        u32 pk1 = (u32)f2bf(acc[2][reg]) | ((u32)f2bf(acc[3][reg]) << 16);
        u32* bp = (u32*)(Asm + pos * 20 + wv * 4);
        bp[0] = pk0; bp[1] = pk1;
    }
    // Wout B-frags: B[k=h][n=d], lane: d=dt*32+lane31, h=half*8+jj
    short8 wfr[2];
#pragma unroll
    for (int dt = 0; dt < 2; dt++) {
        const float* wp = Wout + (dt * 32 + lane31) * 16 + half * 8;
        float4 w0 = *(const float4*)(wp);
        float4 w1 = *(const float4*)(wp + 4);
        short8 t8;
        t8[0]=(short)f2bf(w0.x); t8[1]=(short)f2bf(w0.y); t8[2]=(short)f2bf(w0.z); t8[3]=(short)f2bf(w0.w);
        t8[4]=(short)f2bf(w1.x); t8[5]=(short)f2bf(w1.y); t8[6]=(short)f2bf(w1.z); t8[7]=(short)f2bf(w1.w);
        wfr[dt] = t8;
    }
    // V is j-indexed: same for every i_local -> preload once
    float vreg[2][16];
#pragma unroll
    for (int dt = 0; dt < 2; dt++)
#pragma unroll
        for (int reg = 0; reg < 16; reg++) {
            int row = (reg & 3) + 8 * (reg >> 2) + 4 * half;
            vreg[dt][reg] = V[((size_t)(b * 512 + j0 + row)) * 64 + dt * 32 + lane31];
        }
    __syncthreads();
    // projection: per i_local row (M = 32 j's), N = d
    for (int m = 0; m < 8; m++) {
        int il = wv * 8 + m;
        const u16* ap = Asm + (il * 32 + lane31) * 20 + half * 8;
        union { short8 v; uint2 q[2]; } au;
        au.q[0] = *(const uint2*)(ap);
        au.q[1] = *(const uint2*)(ap + 4);
        int ig = i0 + il;
        size_t rowbase = (size_t)(b * 512 + ig);
#pragma unroll
        for (int dt = 0; dt < 2; dt++) {
            float16 z;
#pragma unroll
            for (int e = 0; e < 16; e++) z[e] = 0.f;
            float16 pa = __builtin_amdgcn_mfma_f32_32x32x16_bf16(au.v, wfr[dt], z, 0, 0, 0);
            float uval = U[rowbase * 64 + dt * 32 + lane31];
            float* ob = out + (rowbase * 512 + j0) * 64 + dt * 32 + lane31;
#pragma unroll
            for (int reg = 0; reg < 16; reg++) {
                int row = (reg & 3) + 8 * (reg >> 2) + 4 * half;   // j_local
                ob[(size_t)row * 64] = pa[reg] + uval + vreg[dt][reg];
            }
        }
    }
}

// ---------------- K5: edge corrections at i==511 / j==511 -------------------
__global__ __launch_bounds__(256) void k_edge(
    const float* __restrict__ dU, const float* __restrict__ dV, float* __restrict__ out)
{
    int t = blockIdx.x * 256 + threadIdx.x;    // 2*4*512*64
    int side = t >> 17;
    int rem = t & 131071;
    int b = rem >> 15;
    int r = (rem >> 6) & 511;
    int d = rem & 63;
    if (side == 0) {                            // column j == 511: + dU[b,i,:]
        size_t o = (((size_t)(b * 512 + r)) * 512 + 511) * 64 + d;
        float add = dU[((size_t)(b * 512 + r)) * 64 + d];
        if (r == 511) add += dV[((size_t)(b * 512 + 511)) * 64 + d];  // corner gets both
        out[o] += add;
    } else if (r != 511) {                      // row i == 511: + dV[b,j,:]
        size_t o = (((size_t)(b * 512 + 511)) * 512 + r) * 64 + d;
        out[o] += dV[((size_t)(b * 512 + r)) * 64 + d];
    }
}

extern "C" void kernel_launch(void* const* d_in, const int* in_sizes, int n_in,
                              void* d_out, int out_size, void* d_ws, size_t ws_size,
                              hipStream_t stream)
{
    const float* x    = (const float*)d_in[0];
    const float* Wq   = (const float*)d_in[1];
    const float* Wk   = (const float*)d_in[2];
    const float* Wpos = (const float*)d_in[3];
    const float* bpos = (const float*)d_in[4];
    const float* qb   = (const float*)d_in[5];
    const float* kb   = (const float*)d_in[6];
    const float* Wout = (const float*)d_in[7];
    const float* bout = (const float*)d_in[8];
    const float* Wyq  = (const float*)d_in[9];
    const float* Wyk  = (const float*)d_in[10];
    float* out = (float*)d_out;
    char* w = (char*)d_ws;
    // workspace layout (~23.3 MB)
    u16* xds   = (u16*)(w + 0);          // 4 MB  [2048][1024] bf16
    u16* g     = (u16*)(w + 4194304);    // 4 MB
    u16* wqb   = (u16*)(w + 8388608);    // 2 MB
    u16* wkb   = (u16*)(w + 10485760);   // 2 MB
    u16* wyqb  = (u16*)(w + 12582912);   // 128 KB
    u16* wykb  = (u16*)(w + 12713984);   // 128 KB
    u16* qA    = (u16*)(w + 12845056);   // 4 MB swizzled
    u16* kB2   = (u16*)(w + 17039360);   // 4 MB swizzled
    float* yqlin = (float*)(w + 21233664); // 512 KB
    float* yklin = (float*)(w + 21757952); // 512 KB
    float* peA   = (float*)(w + 22282240); // 4 KB
    float* peD   = (float*)(w + 22286336); // 4 KB
    float* U     = (float*)(w + 22290432); // 512 KB
    float* V     = (float*)(w + 22814720); // 512 KB
    float* dU    = (float*)(w + 23339008); // 512 KB
    float* dV    = (float*)(w + 23863296); // 512 KB

    k_prep<<<dim3(3076), dim3(256), 0, stream>>>(x, Wq, Wk, Wyq, Wyk, Wpos, bpos,
                                                 xds, g, wqb, wkb, wyqb, wykb, peA, peD);
    k_gemm<<<dim3(34, 16), dim3(256), 0, stream>>>(xds, g, wqb, wkb, wyqb, wykb,
                                                   qA, kB2, yqlin, yklin);
    k_uv<<<dim3(2048), dim3(64), 0, stream>>>(qA, kB2, yqlin, yklin, peA, peD,
                                              qb, kb, Wout, bout, U, V, dU, dV);
    k_main<<<dim3(16, 16, 4), dim3(256), 0, stream>>>(qA, kB2, Wout, U, V, out);
    k_edge<<<dim3(1024), dim3(256), 0, stream>>>(dU, dV, out);
}